// Round 7
// baseline (174.208 us; speedup 1.0000x reference)
//
#include <hip/hip_runtime.h>
#include <hip/hip_bf16.h>
#include <cstdint>

#define DEVI static __device__ __forceinline__

typedef __bf16 bf16x8 __attribute__((ext_vector_type(8)));
typedef float f32x4 __attribute__((ext_vector_type(4)));
typedef float f32x16 __attribute__((ext_vector_type(16)));
typedef unsigned short u16x8 __attribute__((ext_vector_type(8)));

constexpr int Bb = 2, Ll = 4096, Dd = 512, Hh = 8;
constexpr int Mm = Bb * Ll;                      // 8192 rows
constexpr float SCALE2 = 1.4426950408889634f / 22.627416997969522f; // log2(e)/sqrt(512)

// GEMM LDS pitch: 72 shorts = 144B (16B-aligned, 2-way bank aliasing only)
constexpr int PITCH = 72;
constexpr int PITCHB = 144;

DEVI unsigned short f2b(float x) {
  __hip_bfloat16 h = __float2bfloat16(x);
  return *reinterpret_cast<unsigned short*>(&h);
}

// ---------------- fp32 -> bf16 convert (8 elems/thread) ----------------
__global__ void __launch_bounds__(256) cvt_kernel(const float* __restrict__ s,
                                                  unsigned short* __restrict__ d, int n8) {
  int i = blockIdx.x * 256 + threadIdx.x;
  if (i >= n8) return;
  const float4* sp = reinterpret_cast<const float4*>(s) + (size_t)i * 2;
  float4 a = sp[0], b2 = sp[1];
  u16x8 o;
  o[0] = f2b(a.x);  o[1] = f2b(a.y);  o[2] = f2b(a.z);  o[3] = f2b(a.w);
  o[4] = f2b(b2.x); o[5] = f2b(b2.y); o[6] = f2b(b2.z); o[7] = f2b(b2.w);
  *reinterpret_cast<u16x8*>(d + (size_t)i * 8) = o;
}

// ---------------- GEMM: C[M][512] = A[M][512] @ W[512][512]^T ----------------
// z==0 (Q) output is pre-scaled by SCALE2 so attention needs no per-element scale.
__global__ void __launch_bounds__(256, 2) gemm_bt(const unsigned short* __restrict__ Ab,
                                                  const unsigned short* __restrict__ Wb,
                                                  unsigned short* __restrict__ Cb) {
  __shared__ __align__(16) unsigned short As[128 * PITCH];
  __shared__ __align__(16) unsigned short Bs[128 * PITCH];
  const int t = threadIdx.x, lane = t & 63;
  const int w = t >> 6, wm = w >> 1, wn = w & 1;
  const int c = lane & 15, g = lane >> 4;
  const int z = blockIdx.y;
  const unsigned short* A = Ab + (size_t)z * (Mm * Dd);
  const unsigned short* W = Wb + (size_t)z * (Dd * Dd);
  const int tm = (blockIdx.x >> 2) * 128;
  const int tn = (blockIdx.x & 3) * 128;
  const int r0 = t >> 3, c8 = t & 7;

  f32x4 acc[4][4] = {};
  for (int k0 = 0; k0 < Dd; k0 += 64) {
    u16x8 av[4], bv2[4];
#pragma unroll
    for (int u = 0; u < 4; ++u) {
      int r = u * 32 + r0;
      av[u]  = *reinterpret_cast<const u16x8*>(A + (size_t)(tm + r) * Dd + k0 + c8 * 8);
      bv2[u] = *reinterpret_cast<const u16x8*>(W + (size_t)(tn + r) * Dd + k0 + c8 * 8);
    }
#pragma unroll
    for (int u = 0; u < 4; ++u) {
      int r = u * 32 + r0;
      *reinterpret_cast<u16x8*>((char*)As + r * PITCHB + c8 * 16) = av[u];
      *reinterpret_cast<u16x8*>((char*)Bs + r * PITCHB + c8 * 16) = bv2[u];
    }
    __syncthreads();
#pragma unroll
    for (int kk = 0; kk < 2; ++kk) {
      bf16x8 af[4], bfv[4];
#pragma unroll
      for (int mi = 0; mi < 4; ++mi) {
        int row = wm * 64 + mi * 16 + c;
        af[mi] = *reinterpret_cast<const bf16x8*>(
            (const char*)As + row * PITCHB + kk * 64 + g * 16);
      }
#pragma unroll
      for (int ni = 0; ni < 4; ++ni) {
        int row = wn * 64 + ni * 16 + c;
        bfv[ni] = *reinterpret_cast<const bf16x8*>(
            (const char*)Bs + row * PITCHB + kk * 64 + g * 16);
      }
#pragma unroll
      for (int mi = 0; mi < 4; ++mi)
#pragma unroll
        for (int ni = 0; ni < 4; ++ni)
          acc[mi][ni] = __builtin_amdgcn_mfma_f32_16x16x32_bf16(af[mi], bfv[ni], acc[mi][ni], 0, 0, 0);
    }
    __syncthreads();
  }
  const float scl = (z == 0) ? SCALE2 : 1.0f;
  unsigned short* C = Cb + (size_t)z * (Mm * Dd);
#pragma unroll
  for (int mi = 0; mi < 4; ++mi)
#pragma unroll
    for (int j = 0; j < 4; ++j) {
      size_t row = (size_t)(tm + wm * 64 + mi * 16 + g * 4 + j);
      size_t base = row * Dd + tn + wn * 64 + c;
#pragma unroll
      for (int ni = 0; ni < 4; ++ni) C[base + ni * 16] = f2b(acc[mi][ni][j] * scl);
    }
}

// ---------------- V [m][512] -> Vt [b][h][dh=64][L] ----------------
__global__ void __launch_bounds__(256) transpose_v(const unsigned short* __restrict__ V,
                                                   unsigned short* __restrict__ Vt) {
  __shared__ unsigned short s[64][PITCH];
  const int t = threadIdx.x;
  const int bh = blockIdx.y, b = bh >> 3, h = bh & 7;
  const int l0 = blockIdx.x * 64;
  const int r0 = t >> 3, c8 = t & 7;
#pragma unroll
  for (int u = 0; u < 2; ++u) {
    int r = u * 32 + r0;
    u16x8 v = *reinterpret_cast<const u16x8*>(
        V + (size_t)(b * Ll + l0 + r) * Dd + h * 64 + c8 * 8);
#pragma unroll
    for (int e = 0; e < 8; ++e) s[r][c8 * 8 + e] = v[e];
  }
  __syncthreads();
#pragma unroll
  for (int u = 0; u < 2; ++u) {
    int dh = u * 32 + r0;
    int lp = c8 * 8;
    u16x8 o;
#pragma unroll
    for (int e = 0; e < 8; ++e) o[e] = s[lp + e][dh];
    *reinterpret_cast<u16x8*>(Vt + (size_t)(bh * 64 + dh) * Ll + l0 + lp) = o;
  }
}

// ---------------- causal flash attention, 8-wave in-block KV-split ----------
// 512 thr = 8 waves. Waves 0-3 (group 0): key tiles [0,qi+1); waves 4-7
// (group 1): [qi+1, 2qi+2). Same 128 q-rows; 32 q/wave (32x32 swapped MFMA).
// Equal trip counts -> shared __syncthreads is safe. Private K/V dbuf per
// group (64KB); flash-merge of the two partials in LDS at epilogue.
__global__ void __launch_bounds__(512, 4) attn_kernel(const unsigned short* __restrict__ Q,
                                                      const unsigned short* __restrict__ K,
                                                      const unsigned short* __restrict__ Vt,
                                                      float* __restrict__ O) {
  // staging: K g*16384 + par*8192 | V 32768 + g*16384 + par*8192  (64KB)
  // epilogue: f32 eb[2][128][68] = 69632 B
  __shared__ __align__(16) char smem[69632];
  const int t = threadIdx.x, lane = t & 63, w = t >> 6;
  const int g = w >> 2, wq = w & 3;
  const int lq = lane & 31, hi = lane >> 5;
  // block remap: XCD xg owns bh {2xg,2xg+1}; co-resident blocks get qi, 31-qi
  const int bidx = blockIdx.x;
  const int xg = bidx & 7, rr = bidx >> 3, hb = rr >> 5;
  const int bh = 2 * xg + hb;
  int qi = rr & 31; if (hb) qi = 31 - qi;
  const int q0 = qi * 128;
  const int b = bh >> 3, h = bh & 7;

  const int qbase = q0 + wq * 32;
  const int qlane = qbase + lq;

  // Q fragment (B-operand of swapped QK^T); Q is pre-scaled by SCALE2
  const unsigned short* Qrow = Q + (size_t)(b * Ll + qlane) * Dd + h * 64;
  bf16x8 qf[4];
#pragma unroll
  for (int s = 0; s < 4; ++s)
    qf[s] = *reinterpret_cast<const bf16x8*>(Qrow + s * 16 + hi * 8);

  f32x16 oacc[2] = {};
  float m_r = -3e38f, s_r = 0.f;

  const size_t kgbase = (size_t)(b * Ll) * Dd + h * 64;
  const size_t vgbase = (size_t)(bh * 64) * Ll;
  const int Tg = qi + 1;              // tiles per group
  const int kt0 = g * Tg;
  const int ktmax = (qbase + 31) >> 6;
  const int swzl = (lq & 7) << 4;
  const int tg = t & 255;
  const int sr0 = tg >> 3, sc8 = t & 7;
  const int sK = g * 16384;
  const int sV = 32768 + g * 16384;

  // prologue: stage tile kt0 into parity-0 buffers
#pragma unroll
  for (int i = 0; i < 2; ++i) {
    int r = i * 32 + sr0;
    u16x8 kv = *reinterpret_cast<const u16x8*>(
        K + kgbase + (size_t)(kt0 * 64 + r) * Dd + sc8 * 8);
    u16x8 vv = *reinterpret_cast<const u16x8*>(
        Vt + vgbase + (size_t)r * Ll + kt0 * 64 + sc8 * 8);
    int dst = r * 128 + ((sc8 * 16) ^ ((r & 7) << 4));
    *reinterpret_cast<u16x8*>(smem + sK + dst) = kv;
    *reinterpret_cast<u16x8*>(smem + sV + dst) = vv;
  }

  u16x8 kpre[2], vpre[2];
  for (int j = 0; j < Tg; ++j) {
    const int kt = kt0 + j;
    const int par = (j & 1) * 8192;
    __syncthreads();
    const bool pf = (j + 1 < Tg);
    if (pf) {
#pragma unroll
      for (int i = 0; i < 2; ++i) {
        int r = i * 32 + sr0;
        kpre[i] = *reinterpret_cast<const u16x8*>(
            K + kgbase + (size_t)((kt + 1) * 64 + r) * Dd + sc8 * 8);
        vpre[i] = *reinterpret_cast<const u16x8*>(
            Vt + vgbase + (size_t)r * Ll + (kt + 1) * 64 + sc8 * 8);
      }
    }
    if (kt <= ktmax) {
      const char* Kc = smem + sK + par;
      const char* Vc = smem + sV + par;
      // QK^T swapped: sacc[fi] = S^T for keys 32fi..32fi+31 x q-cols
      f32x16 sacc[2] = {};
      __builtin_amdgcn_s_setprio(1);
#pragma unroll
      for (int s = 0; s < 4; ++s) {
        int off = (s * 32 + hi * 16) ^ swzl;
        bf16x8 k0 = *reinterpret_cast<const bf16x8*>(Kc + lq * 128 + off);
        bf16x8 k1 = *reinterpret_cast<const bf16x8*>(Kc + (lq + 32) * 128 + off);
        sacc[0] = __builtin_amdgcn_mfma_f32_32x32x16_bf16(k0, qf[s], sacc[0], 0, 0, 0);
        sacc[1] = __builtin_amdgcn_mfma_f32_32x32x16_bf16(k1, qf[s], sacc[1], 0, 0, 0);
      }
      __builtin_amdgcn_s_setprio(0);
      // lane's S: S[q=qlane][key = kt*64 + 32fi + (r&3)+8*(r>>2)+4*hi]
      float p[2][16];
      if (kt * 64 + 63 > qbase) {
#pragma unroll
        for (int fi = 0; fi < 2; ++fi)
#pragma unroll
          for (int r = 0; r < 16; ++r) {
            int key = kt * 64 + 32 * fi + (r & 3) + 8 * (r >> 2) + 4 * hi;
            p[fi][r] = (key > qlane) ? -3e38f : sacc[fi][r];
          }
      } else {
#pragma unroll
        for (int fi = 0; fi < 2; ++fi)
#pragma unroll
          for (int r = 0; r < 16; ++r) p[fi][r] = sacc[fi][r];
      }
      // tree max (depth 5)
      float mx[16];
#pragma unroll
      for (int r = 0; r < 16; ++r) mx[r] = fmaxf(p[0][r], p[1][r]);
#pragma unroll
      for (int s = 8; s >= 1; s >>= 1)
#pragma unroll
        for (int r = 0; r < 8; ++r) if (r < s) mx[r] = fmaxf(mx[r], mx[r + s]);
      float pmax = fmaxf(mx[0], __shfl_xor(mx[0], 32));
      // defer-max (T13, THR=8)
      float alpha = 1.0f;
      if (!__all(pmax <= m_r + 8.0f)) {
        float mn = fmaxf(m_r, pmax);
        alpha = exp2f(m_r - mn);
        m_r = mn;
#pragma unroll
        for (int fo = 0; fo < 2; ++fo)
#pragma unroll
          for (int r = 0; r < 16; ++r) oacc[fo][r] *= alpha;
      }
      // exp + tree sum
#pragma unroll
      for (int fi = 0; fi < 2; ++fi)
#pragma unroll
        for (int r = 0; r < 16; ++r) p[fi][r] = exp2f(p[fi][r] - m_r);
      float sm[16];
#pragma unroll
      for (int r = 0; r < 16; ++r) sm[r] = p[0][r] + p[1][r];
#pragma unroll
      for (int s = 8; s >= 1; s >>= 1)
#pragma unroll
        for (int r = 0; r < 8; ++r) if (r < s) sm[r] += sm[r + s];
      float rs = sm[0] + __shfl_xor(sm[0], 32);
      s_r = s_r * alpha + rs;
      // pack P to bf16 pairs
      unsigned wpk[2][4][2], ppk[2][4][2];
#pragma unroll
      for (int fi = 0; fi < 2; ++fi)
#pragma unroll
        for (int u = 0; u < 4; ++u) {
          wpk[fi][u][0] = (unsigned)f2b(p[fi][4 * u + 0]) | ((unsigned)f2b(p[fi][4 * u + 1]) << 16);
          wpk[fi][u][1] = (unsigned)f2b(p[fi][4 * u + 2]) | ((unsigned)f2b(p[fi][4 * u + 3]) << 16);
          ppk[fi][u][0] = __shfl_xor(wpk[fi][u][0], 32);
          ppk[fi][u][1] = __shfl_xor(wpk[fi][u][1], 32);
        }
      // PV swapped
      __builtin_amdgcn_s_setprio(1);
#pragma unroll
      for (int sp = 0; sp < 4; ++sp) {
        const int fi = sp >> 1, u0 = 2 * (sp & 1), u1 = u0 + 1;
        unsigned d0 = hi ? ppk[fi][u1][0] : wpk[fi][u0][0];
        unsigned d1 = hi ? ppk[fi][u1][1] : wpk[fi][u0][1];
        unsigned d2 = hi ? wpk[fi][u1][0] : ppk[fi][u0][0];
        unsigned d3 = hi ? wpk[fi][u1][1] : ppk[fi][u0][1];
        uint4 bdw = make_uint4(d0, d1, d2, d3);
        bf16x8 bp = *reinterpret_cast<bf16x8*>(&bdw);
        int off = (sp * 32 + hi * 16) ^ swzl;
        bf16x8 v0 = *reinterpret_cast<const bf16x8*>(Vc + lq * 128 + off);
        bf16x8 v1 = *reinterpret_cast<const bf16x8*>(Vc + (lq + 32) * 128 + off);
        oacc[0] = __builtin_amdgcn_mfma_f32_32x32x16_bf16(v0, bp, oacc[0], 0, 0, 0);
        oacc[1] = __builtin_amdgcn_mfma_f32_32x32x16_bf16(v1, bp, oacc[1], 0, 0, 0);
      }
      __builtin_amdgcn_s_setprio(0);
    }
    if (pf) {
      const int nxt = ((j + 1) & 1) * 8192;
#pragma unroll
      for (int i = 0; i < 2; ++i) {
        int r = i * 32 + sr0;
        int dst = r * 128 + ((sc8 * 16) ^ ((r & 7) << 4));
        *reinterpret_cast<u16x8*>(smem + sK + nxt + dst) = kpre[i];
        *reinterpret_cast<u16x8*>(smem + sV + nxt + dst) = vpre[i];
      }
    }
  }
  // ---- epilogue: write partials to LDS, flash-merge, coalesced store ----
  __syncthreads();
  float* eb = reinterpret_cast<float*>(smem);   // [2][128][68]
  const int prow = g * 128 + wq * 32 + lq;
#pragma unroll
  for (int fo = 0; fo < 2; ++fo)
#pragma unroll
    for (int u = 0; u < 4; ++u) {
      int dh = 32 * fo + 8 * u + 4 * hi;
      float4 v4 = make_float4(oacc[fo][4 * u + 0], oacc[fo][4 * u + 1],
                              oacc[fo][4 * u + 2], oacc[fo][4 * u + 3]);
      *reinterpret_cast<float4*>(&eb[prow * 68 + dh]) = v4;
    }
  eb[prow * 68 + 64] = m_r;   // both hi-lanes write identical values
  eb[prow * 68 + 65] = s_r;
  __syncthreads();
  const int row = t >> 2, q4 = t & 3;
  const float m1 = eb[row * 68 + 64], s1 = eb[row * 68 + 65];
  const float m2 = eb[(128 + row) * 68 + 64], s2 = eb[(128 + row) * 68 + 65];
  const float m = fmaxf(m1, m2);
  const float a1 = exp2f(m1 - m), a2 = exp2f(m2 - m);
  const float inv = 1.0f / (s1 * a1 + s2 * a2);
  float* orow = O + (size_t)(b * Ll + q0 + row) * Dd + h * 64 + q4 * 16;
#pragma unroll
  for (int jj = 0; jj < 4; ++jj) {
    float4 o1 = *reinterpret_cast<const float4*>(&eb[row * 68 + q4 * 16 + jj * 4]);
    float4 o2 = *reinterpret_cast<const float4*>(&eb[(128 + row) * 68 + q4 * 16 + jj * 4]);
    float4 o;
    o.x = (o1.x * a1 + o2.x * a2) * inv;
    o.y = (o1.y * a1 + o2.y * a2) * inv;
    o.z = (o1.z * a1 + o2.z * a2) * inv;
    o.w = (o1.w * a1 + o2.w * a2) * inv;
    *reinterpret_cast<float4*>(orow + jj * 4) = o;
  }
}

// ---------------- launcher ----------------
extern "C" void kernel_launch(void* const* d_in, const int* in_sizes, int n_in,
                              void* d_out, int out_size, void* d_ws, size_t ws_size,
                              hipStream_t stream) {
  const float* query = (const float*)d_in[0];
  const float* key   = (const float*)d_in[1];
  const float* value = (const float*)d_in[2];
  // d_in[3] = causal mask (implied by kernel; unused)
  const float* Wq = (const float*)d_in[4];
  const float* Wk = (const float*)d_in[5];
  const float* Wv = (const float*)d_in[6];
  // d_in[7] = Wo -- present in inputs but NOT used by the reference

  unsigned short* Xbf  = (unsigned short*)d_ws;                 // 3 x M x D
  unsigned short* Wbf  = Xbf + (size_t)3 * Mm * Dd;             // 3 x D x D
  unsigned short* QKV  = Wbf + (size_t)3 * Dd * Dd;             // 3 x M x D
  unsigned short* Vt   = QKV + (size_t)3 * Mm * Dd;             // B*H*64 x L

  const int nbig = Mm * Dd / 8, nsmall = Dd * Dd / 8;
  cvt_kernel<<<nbig / 256, 256, 0, stream>>>(query, Xbf, nbig);
  cvt_kernel<<<nbig / 256, 256, 0, stream>>>(key,   Xbf + (size_t)Mm * Dd, nbig);
  cvt_kernel<<<nbig / 256, 256, 0, stream>>>(value, Xbf + (size_t)2 * Mm * Dd, nbig);
  cvt_kernel<<<nsmall / 256, 256, 0, stream>>>(Wq, Wbf, nsmall);
  cvt_kernel<<<nsmall / 256, 256, 0, stream>>>(Wk, Wbf + (size_t)Dd * Dd, nsmall);
  cvt_kernel<<<nsmall / 256, 256, 0, stream>>>(Wv, Wbf + (size_t)2 * Dd * Dd, nsmall);

  gemm_bt<<<dim3(256, 3), 256, 0, stream>>>(Xbf, Wbf, QKV);

  unsigned short* Qb = QKV;
  unsigned short* Kb = QKV + (size_t)Mm * Dd;
  unsigned short* Vb = QKV + (size_t)2 * Mm * Dd;
  transpose_v<<<dim3(64, 16), 256, 0, stream>>>(Vb, Vt);
  attn_kernel<<<512, 512, 0, stream>>>(Qb, Kb, Vt, (float*)d_out);
}

// Round 8
// 150.419 us; speedup vs baseline: 1.1581x; 1.1581x over previous
//
#include <hip/hip_runtime.h>
#include <hip/hip_bf16.h>
#include <cstdint>

#define DEVI static __device__ __forceinline__

typedef __bf16 bf16x8 __attribute__((ext_vector_type(8)));
typedef float f32x4 __attribute__((ext_vector_type(4)));
typedef float f32x16 __attribute__((ext_vector_type(16)));
typedef unsigned short u16x8 __attribute__((ext_vector_type(8)));

constexpr int Bb = 2, Ll = 4096, Dd = 512, Hh = 8;
constexpr int Mm = Bb * Ll;                      // 8192 rows
constexpr float SCALE2 = 1.4426950408889634f / 22.627416997969522f; // log2(e)/sqrt(512)

// GEMM LDS pitch: 72 shorts = 144B (16B-aligned, 2-way bank aliasing only)
constexpr int PITCH = 72;
constexpr int PITCHB = 144;

DEVI unsigned short f2b(float x) {
  __hip_bfloat16 h = __float2bfloat16(x);
  return *reinterpret_cast<unsigned short*>(&h);
}

DEVI void gll16(const void* g, void* l) {
  __builtin_amdgcn_global_load_lds((const __attribute__((address_space(1))) void*)g,
                                   (__attribute__((address_space(3))) void*)l, 16, 0, 0);
}

// ---------------- fp32 -> bf16 convert (8 elems/thread) ----------------
__global__ void __launch_bounds__(256) cvt_kernel(const float* __restrict__ s,
                                                  unsigned short* __restrict__ d, int n8) {
  int i = blockIdx.x * 256 + threadIdx.x;
  if (i >= n8) return;
  const float4* sp = reinterpret_cast<const float4*>(s) + (size_t)i * 2;
  float4 a = sp[0], b2 = sp[1];
  u16x8 o;
  o[0] = f2b(a.x);  o[1] = f2b(a.y);  o[2] = f2b(a.z);  o[3] = f2b(a.w);
  o[4] = f2b(b2.x); o[5] = f2b(b2.y); o[6] = f2b(b2.z); o[7] = f2b(b2.w);
  *reinterpret_cast<u16x8*>(d + (size_t)i * 8) = o;
}

// ---------------- GEMM: C[M][512] = A[M][512] @ W[512][512]^T ----------------
// z==0 (Q): output pre-scaled by SCALE2. z==2 (V): output written TRANSPOSED
// into Vt[b*512+col][l] (fuses the old transpose_v kernel).
__global__ void __launch_bounds__(256, 2) gemm_bt(const unsigned short* __restrict__ Ab,
                                                  const unsigned short* __restrict__ Wb,
                                                  unsigned short* __restrict__ Cb,
                                                  unsigned short* __restrict__ VtOut) {
  __shared__ __align__(16) unsigned short As[128 * PITCH];
  __shared__ __align__(16) unsigned short Bs[128 * PITCH];
  const int t = threadIdx.x, lane = t & 63;
  const int w = t >> 6, wm = w >> 1, wn = w & 1;
  const int c = lane & 15, g = lane >> 4;
  const int z = blockIdx.y;
  const unsigned short* A = Ab + (size_t)z * (Mm * Dd);
  const unsigned short* W = Wb + (size_t)z * (Dd * Dd);
  const int tm = (blockIdx.x >> 2) * 128;
  const int tn = (blockIdx.x & 3) * 128;
  const int r0 = t >> 3, c8 = t & 7;

  f32x4 acc[4][4] = {};
  for (int k0 = 0; k0 < Dd; k0 += 64) {
    u16x8 av[4], bv2[4];
#pragma unroll
    for (int u = 0; u < 4; ++u) {
      int r = u * 32 + r0;
      av[u]  = *reinterpret_cast<const u16x8*>(A + (size_t)(tm + r) * Dd + k0 + c8 * 8);
      bv2[u] = *reinterpret_cast<const u16x8*>(W + (size_t)(tn + r) * Dd + k0 + c8 * 8);
    }
#pragma unroll
    for (int u = 0; u < 4; ++u) {
      int r = u * 32 + r0;
      *reinterpret_cast<u16x8*>((char*)As + r * PITCHB + c8 * 16) = av[u];
      *reinterpret_cast<u16x8*>((char*)Bs + r * PITCHB + c8 * 16) = bv2[u];
    }
    __syncthreads();
#pragma unroll
    for (int kk = 0; kk < 2; ++kk) {
      bf16x8 af[4], bfv[4];
#pragma unroll
      for (int mi = 0; mi < 4; ++mi) {
        int row = wm * 64 + mi * 16 + c;
        af[mi] = *reinterpret_cast<const bf16x8*>(
            (const char*)As + row * PITCHB + kk * 64 + g * 16);
      }
#pragma unroll
      for (int ni = 0; ni < 4; ++ni) {
        int row = wn * 64 + ni * 16 + c;
        bfv[ni] = *reinterpret_cast<const bf16x8*>(
            (const char*)Bs + row * PITCHB + kk * 64 + g * 16);
      }
#pragma unroll
      for (int mi = 0; mi < 4; ++mi)
#pragma unroll
        for (int ni = 0; ni < 4; ++ni)
          acc[mi][ni] = __builtin_amdgcn_mfma_f32_16x16x32_bf16(af[mi], bfv[ni], acc[mi][ni], 0, 0, 0);
    }
    __syncthreads();
  }
  if (z == 2) {
    // transposed write: Vt[(b*512 + col)][l], l = row & 4095, b = row >> 12
#pragma unroll
    for (int mi = 0; mi < 4; ++mi)
#pragma unroll
      for (int j = 0; j < 4; ++j) {
        int row = tm + wm * 64 + mi * 16 + g * 4 + j;
        int bb = row >> 12, l = row & 4095;
#pragma unroll
        for (int ni = 0; ni < 4; ++ni) {
          int col = tn + wn * 64 + c + ni * 16;
          VtOut[(size_t)(bb * 512 + col) * Ll + l] = f2b(acc[mi][ni][j]);
        }
      }
  } else {
    const float scl = (z == 0) ? SCALE2 : 1.0f;
    unsigned short* C = Cb + (size_t)z * (Mm * Dd);
#pragma unroll
    for (int mi = 0; mi < 4; ++mi)
#pragma unroll
      for (int j = 0; j < 4; ++j) {
        size_t row = (size_t)(tm + wm * 64 + mi * 16 + g * 4 + j);
        size_t base = row * Dd + tn + wn * 64 + c;
#pragma unroll
        for (int ni = 0; ni < 4; ++ni) C[base + ni * 16] = f2b(acc[mi][ni][j] * scl);
      }
  }
}

// ---------------- causal flash attention, 8-wave in-block KV-split ----------
// 512 thr = 8 waves; waves 0-3 (group 0): key tiles [0,qi+1); waves 4-7
// (group 1): [qi+1, 2qi+2). Same 128 q-rows, 32 q/wave (32x32 swapped MFMA).
// K/V staged via global_load_lds (linear dest, pre-swizzled source), double
// buffered per group; raw s_barrier + vmcnt(0) (no full drain). Flash-merge
// of the two group partials in LDS at epilogue.
__global__ void __launch_bounds__(512)
__attribute__((amdgpu_waves_per_eu(4, 4)))
attn_kernel(const unsigned short* __restrict__ Q,
            const unsigned short* __restrict__ K,
            const unsigned short* __restrict__ Vt,
            float* __restrict__ O) {
  // staging: K at g*16384 + par*8192, V at 32768 + g*16384 + par*8192 (64KB)
  // epilogue: f32 eb[2][128][68] = 69632 B (reuses the staging region)
  __shared__ __align__(16) char smem[69632];
  const int t = threadIdx.x, lane = t & 63, w = t >> 6;
  const int g = w >> 2, wq = w & 3;
  const int lq = lane & 31, hi = lane >> 5;
  // block remap: XCD xg owns bh {2xg,2xg+1}; co-resident blocks get qi, 31-qi
  const int bidx = blockIdx.x;
  const int xg = bidx & 7, rr = bidx >> 3, hb = rr >> 5;
  const int bh = 2 * xg + hb;
  int qi = rr & 31; if (hb) qi = 31 - qi;
  const int q0 = qi * 128;
  const int b = bh >> 3, h = bh & 7;

  const int qbase = q0 + wq * 32;
  const int qlane = qbase + lq;

  // Q fragment (B-operand of swapped QK^T); Q is pre-scaled by SCALE2
  const unsigned short* Qrow = Q + (size_t)(b * Ll + qlane) * Dd + h * 64;
  bf16x8 qf[4];
#pragma unroll
  for (int s = 0; s < 4; ++s)
    qf[s] = *reinterpret_cast<const bf16x8*>(Qrow + s * 16 + hi * 8);

  f32x16 oacc[2] = {};
  float m_r = -3e38f, s_r = 0.f;

  const size_t kgbase = (size_t)(b * Ll) * Dd + h * 64;
  const size_t vgbase = (size_t)(bh * 64) * Ll;
  const int Tg = qi + 1;              // tiles per group
  const int kt0 = g * Tg;
  const int ktmax = (qbase + 31) >> 6;
  const int swzl = (lq & 7) << 4;
  const int tg = t & 255;
  const int sr0 = tg >> 3, sc8 = tg & 7;
  const int sK = g * 16384;
  const int sV = 32768 + g * 16384;

  // stage one 64-key tile into parity buffer `par` via global_load_lds.
  // LDS dest is LINEAR (r*128 + sc8*16); the XOR swizzle is applied to the
  // global SOURCE column, so reads with off^swzl(row) see K[row][off].
  auto STAGE = [&](int par, int kt) {
#pragma unroll
    for (int i = 0; i < 2; ++i) {
      int r = i * 32 + sr0;
      int srcb = (sc8 * 16) ^ ((r & 7) << 4);   // byte col within 128B row
      gll16(K + kgbase + (size_t)(kt * 64 + r) * Dd + (srcb >> 1),
            smem + sK + par + r * 128 + sc8 * 16);
      gll16(Vt + vgbase + (size_t)r * Ll + kt * 64 + (srcb >> 1),
            smem + sV + par + r * 128 + sc8 * 16);
    }
  };

  STAGE(0, kt0);
  for (int j = 0; j < Tg; ++j) {
    const int kt = kt0 + j;
    const int par = (j & 1) * 8192;
    asm volatile("s_waitcnt vmcnt(0)" ::: "memory");  // cur tile landed in LDS
    __builtin_amdgcn_s_barrier();                     // all waves' stages done
    __builtin_amdgcn_sched_barrier(0);
    if (j + 1 < Tg) STAGE(((j + 1) & 1) * 8192, kt + 1);  // lands during compute
    if (kt <= ktmax) {
      const char* Kc = smem + sK + par;
      const char* Vc = smem + sV + par;
      // QK^T swapped: sacc[fi] = S^T for keys 32fi..32fi+31 x q-cols
      f32x16 sacc[2] = {};
      __builtin_amdgcn_s_setprio(1);
#pragma unroll
      for (int s = 0; s < 4; ++s) {
        int off = (s * 32 + hi * 16) ^ swzl;
        bf16x8 k0 = *reinterpret_cast<const bf16x8*>(Kc + lq * 128 + off);
        bf16x8 k1 = *reinterpret_cast<const bf16x8*>(Kc + (lq + 32) * 128 + off);
        sacc[0] = __builtin_amdgcn_mfma_f32_32x32x16_bf16(k0, qf[s], sacc[0], 0, 0, 0);
        sacc[1] = __builtin_amdgcn_mfma_f32_32x32x16_bf16(k1, qf[s], sacc[1], 0, 0, 0);
      }
      __builtin_amdgcn_s_setprio(0);
      // lane's S: S[q=qlane][key = kt*64 + 32fi + (r&3)+8*(r>>2)+4*hi]
      float p[2][16];
      if (kt * 64 + 63 > qbase) {
#pragma unroll
        for (int fi = 0; fi < 2; ++fi)
#pragma unroll
          for (int r = 0; r < 16; ++r) {
            int key = kt * 64 + 32 * fi + (r & 3) + 8 * (r >> 2) + 4 * hi;
            p[fi][r] = (key > qlane) ? -3e38f : sacc[fi][r];
          }
      } else {
#pragma unroll
        for (int fi = 0; fi < 2; ++fi)
#pragma unroll
          for (int r = 0; r < 16; ++r) p[fi][r] = sacc[fi][r];
      }
      // tree max (depth 5)
      float mx[16];
#pragma unroll
      for (int r = 0; r < 16; ++r) mx[r] = fmaxf(p[0][r], p[1][r]);
#pragma unroll
      for (int s = 8; s >= 1; s >>= 1)
#pragma unroll
        for (int r = 0; r < 8; ++r) if (r < s) mx[r] = fmaxf(mx[r], mx[r + s]);
      float pmax = fmaxf(mx[0], __shfl_xor(mx[0], 32));
      // defer-max (T13, THR=8)
      float alpha = 1.0f;
      if (!__all(pmax <= m_r + 8.0f)) {
        float mn = fmaxf(m_r, pmax);
        alpha = exp2f(m_r - mn);
        m_r = mn;
#pragma unroll
        for (int fo = 0; fo < 2; ++fo)
#pragma unroll
          for (int r = 0; r < 16; ++r) oacc[fo][r] *= alpha;
      }
      // exp + tree sum
#pragma unroll
      for (int fi = 0; fi < 2; ++fi)
#pragma unroll
        for (int r = 0; r < 16; ++r) p[fi][r] = exp2f(p[fi][r] - m_r);
      float sm[16];
#pragma unroll
      for (int r = 0; r < 16; ++r) sm[r] = p[0][r] + p[1][r];
#pragma unroll
      for (int s = 8; s >= 1; s >>= 1)
#pragma unroll
        for (int r = 0; r < 8; ++r) if (r < s) sm[r] += sm[r + s];
      float rs = sm[0] + __shfl_xor(sm[0], 32);
      s_r = s_r * alpha + rs;
      // pack P to bf16 pairs
      unsigned wpk[2][4][2], ppk[2][4][2];
#pragma unroll
      for (int fi = 0; fi < 2; ++fi)
#pragma unroll
        for (int u = 0; u < 4; ++u) {
          wpk[fi][u][0] = (unsigned)f2b(p[fi][4 * u + 0]) | ((unsigned)f2b(p[fi][4 * u + 1]) << 16);
          wpk[fi][u][1] = (unsigned)f2b(p[fi][4 * u + 2]) | ((unsigned)f2b(p[fi][4 * u + 3]) << 16);
          ppk[fi][u][0] = __shfl_xor(wpk[fi][u][0], 32);
          ppk[fi][u][1] = __shfl_xor(wpk[fi][u][1], 32);
        }
      // PV swapped
      __builtin_amdgcn_s_setprio(1);
#pragma unroll
      for (int sp = 0; sp < 4; ++sp) {
        const int fi = sp >> 1, u0 = 2 * (sp & 1), u1 = u0 + 1;
        unsigned d0 = hi ? ppk[fi][u1][0] : wpk[fi][u0][0];
        unsigned d1 = hi ? ppk[fi][u1][1] : wpk[fi][u0][1];
        unsigned d2 = hi ? wpk[fi][u1][0] : ppk[fi][u0][0];
        unsigned d3 = hi ? wpk[fi][u1][1] : ppk[fi][u0][1];
        uint4 bdw = make_uint4(d0, d1, d2, d3);
        bf16x8 bp = *reinterpret_cast<bf16x8*>(&bdw);
        int off = (sp * 32 + hi * 16) ^ swzl;
        bf16x8 v0 = *reinterpret_cast<const bf16x8*>(Vc + lq * 128 + off);
        bf16x8 v1 = *reinterpret_cast<const bf16x8*>(Vc + (lq + 32) * 128 + off);
        oacc[0] = __builtin_amdgcn_mfma_f32_32x32x16_bf16(v0, bp, oacc[0], 0, 0, 0);
        oacc[1] = __builtin_amdgcn_mfma_f32_32x32x16_bf16(v1, bp, oacc[1], 0, 0, 0);
      }
      __builtin_amdgcn_s_setprio(0);
    }
  }
  // ---- epilogue: write partials to LDS, flash-merge, coalesced store ----
  __syncthreads();
  float* eb = reinterpret_cast<float*>(smem);   // [2][128][68]
  const int prow = g * 128 + wq * 32 + lq;
#pragma unroll
  for (int fo = 0; fo < 2; ++fo)
#pragma unroll
    for (int u = 0; u < 4; ++u) {
      int dh = 32 * fo + 8 * u + 4 * hi;
      float4 v4 = make_float4(oacc[fo][4 * u + 0], oacc[fo][4 * u + 1],
                              oacc[fo][4 * u + 2], oacc[fo][4 * u + 3]);
      *reinterpret_cast<float4*>(&eb[prow * 68 + dh]) = v4;
    }
  eb[prow * 68 + 64] = m_r;   // both hi-lanes write identical values
  eb[prow * 68 + 65] = s_r;
  __syncthreads();
  const int row = t >> 2, q4 = t & 3;
  const float m1 = eb[row * 68 + 64], s1 = eb[row * 68 + 65];
  const float m2 = eb[(128 + row) * 68 + 64], s2 = eb[(128 + row) * 68 + 65];
  const float m = fmaxf(m1, m2);
  const float a1 = exp2f(m1 - m), a2 = exp2f(m2 - m);
  const float inv = 1.0f / (s1 * a1 + s2 * a2);
  float* orow = O + (size_t)(b * Ll + q0 + row) * Dd + h * 64 + q4 * 16;
#pragma unroll
  for (int jj = 0; jj < 4; ++jj) {
    float4 o1 = *reinterpret_cast<const float4*>(&eb[row * 68 + q4 * 16 + jj * 4]);
    float4 o2 = *reinterpret_cast<const float4*>(&eb[(128 + row) * 68 + q4 * 16 + jj * 4]);
    float4 o;
    o.x = (o1.x * a1 + o2.x * a2) * inv;
    o.y = (o1.y * a1 + o2.y * a2) * inv;
    o.z = (o1.z * a1 + o2.z * a2) * inv;
    o.w = (o1.w * a1 + o2.w * a2) * inv;
    *reinterpret_cast<float4*>(orow + jj * 4) = o;
  }
}

// ---------------- launcher ----------------
extern "C" void kernel_launch(void* const* d_in, const int* in_sizes, int n_in,
                              void* d_out, int out_size, void* d_ws, size_t ws_size,
                              hipStream_t stream) {
  const float* query = (const float*)d_in[0];
  const float* key   = (const float*)d_in[1];
  const float* value = (const float*)d_in[2];
  // d_in[3] = causal mask (implied by kernel; unused)
  const float* Wq = (const float*)d_in[4];
  const float* Wk = (const float*)d_in[5];
  const float* Wv = (const float*)d_in[6];
  // d_in[7] = Wo -- present in inputs but NOT used by the reference

  unsigned short* Xbf  = (unsigned short*)d_ws;                 // 3 x M x D
  unsigned short* Wbf  = Xbf + (size_t)3 * Mm * Dd;             // 3 x D x D
  unsigned short* QKV  = Wbf + (size_t)3 * Dd * Dd;             // 3 x M x D (V slot unused)
  unsigned short* Vt   = QKV + (size_t)3 * Mm * Dd;             // B*H*64 x L

  const int nbig = Mm * Dd / 8, nsmall = Dd * Dd / 8;
  cvt_kernel<<<nbig / 256, 256, 0, stream>>>(query, Xbf, nbig);
  cvt_kernel<<<nbig / 256, 256, 0, stream>>>(key,   Xbf + (size_t)Mm * Dd, nbig);
  cvt_kernel<<<nbig / 256, 256, 0, stream>>>(value, Xbf + (size_t)2 * Mm * Dd, nbig);
  cvt_kernel<<<nsmall / 256, 256, 0, stream>>>(Wq, Wbf, nsmall);
  cvt_kernel<<<nsmall / 256, 256, 0, stream>>>(Wk, Wbf + (size_t)Dd * Dd, nsmall);
  cvt_kernel<<<nsmall / 256, 256, 0, stream>>>(Wv, Wbf + (size_t)2 * Dd * Dd, nsmall);

  gemm_bt<<<dim3(256, 3), 256, 0, stream>>>(Xbf, Wbf, QKV, Vt);

  unsigned short* Qb = QKV;
  unsigned short* Kb = QKV + (size_t)Mm * Dd;
  attn_kernel<<<512, 512, 0, stream>>>(Qb, Kb, Vt, (float*)d_out);
}